// Round 1
// 362.640 us; speedup vs baseline: 1.0925x; 1.0925x over previous
//
#include <hip/hip_runtime.h>
#include <hip/hip_fp16.h>

// GCN 2-layer: N=200000, E=6400000, 14 -> 16(relu) -> 2.
// Round 13: k_binA write-amplification fix. WRITE_SIZE was 104MB vs 25.6MB
// logical (4x): per-tile bucket chunks (~52B) share 64B lines across blocks on
// DIFFERENT XCDs -> HBM line ping-pong (partial writeback + RFO refetch).
//   - buckets now have 8 sub-segments keyed by blockIdx.x&7 (~= XCD under
//     round-robin dispatch; locality heuristic only, correctness-independent).
//     All writers of a sub-segment share one L2 -> partial appends merge in L2,
//     each binned line written back once, full. Also 8x less gcur contention.
//   - binA edge loads pair-vectorized (ulonglong2: 2 edges / 16B load).
//   - k_sort reads 8 sub-segments; rank-capture replaced by count->scan->
//     cursor-atomic scatter (cnt[] reused as cursor) to keep VGPRs low.
// Pipeline: init -> binA -> sort(+dinv) -> prep -> agg1(2 phase) -> mlp -> agg2.

constexpr int NN = 200000;
constexpr int NE = 6400000;
constexpr int IC = 14;
constexpr int HC = 16;
constexpr int OC = 2;

constexpr int NBK = 392;                   // buckets of 512 dst nodes
constexpr int NSUB = 8;                    // sub-segments per bucket (bid&7)
constexpr int SCAP = 2816;                 // per (sub,bucket) cap: mean 2058 + 16.7 sigma
constexpr int NSEG = NSUB * NBK;           // 3136 segments
constexpr int CCAP = NSUB * SCAP;          // 22528 csr per-bucket capacity
constexpr int TILE = 5120;                 // edges per binA tile
constexpr int IPT = TILE / 256;            // 20
constexpr int IPT2 = IPT / 2;              // 10 pair-loads per thread
constexpr int NTILE = NE / TILE;           // 1250
constexpr int OVFCAP = 65536;
constexpr int NB = (NN + 255) / 256;       // 782
constexpr int NAGG = NN / 64;              // 3125 blocks per phase
constexpr unsigned PHB = 100000u;          // phase boundary on src
constexpr int GSTR = 16;                   // gcur stride: 1 counter per 64B line

typedef unsigned long long ull;

// init gcur (padded) + ovf counter + dtype flag
__global__ void k_init(int* __restrict__ gcur, const void* __restrict__ ei,
                       int* __restrict__ flag) {
    int i = blockIdx.x * blockDim.x + threadIdx.x;
    if (i < NSEG) gcur[i * GSTR] = i * SCAP;
    else if (i == NSEG) gcur[i * GSTR] = 0;  // overflow counter
    if (i == 500) {  // one thread sniffs edge dtype
        const ull* p = (const ull*)ei;
        ull acc = 0ULL;
        for (int k = 0; k < 64; ++k) acc |= (p[k] >> 32);
        *flag = (acc == 0ULL) ? 1 : 0;  // 1 => int64 indices, 0 => int32
    }
}

// Bin edges by dst>>9 into per-(sub,bucket) global segments, sub = bid&7.
// Rank captured from the histogram atomic; LDS-staged for coalesced segment
// write-out. Bucket of a stage slot recovered by binary search over lofs.
__global__ __launch_bounds__(256, 6) void k_binA(const void* __restrict__ ei,
                                                 const int* __restrict__ flag,
                                                 int* __restrict__ gcur,
                                                 unsigned* __restrict__ binned,
                                                 ull* __restrict__ ovf) {
    __shared__ int hist[NBK];
    __shared__ int lofs[NBK];
    __shared__ int gofs[NBK];
    __shared__ int wsum[4];
    __shared__ unsigned stage[TILE];

    int t = threadIdx.x;
    int fl = *flag;
    int tile0 = blockIdx.x * TILE;
    int segbase = (blockIdx.x & (NSUB - 1)) * NBK;

    if (t < NBK) hist[t] = 0;
    if (t + 256 < NBK) hist[t + 256] = 0;
    __syncthreads();

    // pass 1: dst pairs (16B loads) + rank capture (dr = rank<<18 | dst)
    unsigned dr[IPT];
#pragma unroll
    for (int k = 0; k < IPT2; ++k) {
        int e = tile0 + k * 512 + 2 * t;
        int d0, d1;
        if (fl) {
            ulonglong2 dd = *(const ulonglong2*)((const long long*)ei + NE + e);
            d0 = (int)dd.x;
            d1 = (int)dd.y;
        } else {
            uint2 dd = *(const uint2*)((const int*)ei + NE + e);
            d0 = (int)dd.x;
            d1 = (int)dd.y;
        }
        int r0 = atomicAdd(&hist[d0 >> 9], 1);
        int r1 = atomicAdd(&hist[d1 >> 9], 1);
        dr[2 * k] = ((unsigned)r0 << 18) | (unsigned)d0;
        dr[2 * k + 1] = ((unsigned)r1 << 18) | (unsigned)d1;
    }
    __syncthreads();

    // exclusive scan of 392 counts: pair-sum + 64-lane shfl scan + wave combine
    int h0 = 0, h1 = 0, p = 0;
    if (t < NBK / 2) {
        h0 = hist[2 * t];
        h1 = hist[2 * t + 1];
        p = h0 + h1;
    }
    int lane = t & 63;
    int w = t >> 6;
    int incl = p;
#pragma unroll
    for (int off = 1; off < 64; off <<= 1) {
        int v = __shfl_up(incl, off, 64);
        if (lane >= off) incl += v;
    }
    if (lane == 63) wsum[w] = incl;
    __syncthreads();
    int wbase = 0;
#pragma unroll
    for (int ww = 0; ww < 4; ++ww) wbase += (ww < w) ? wsum[ww] : 0;
    int ex = wbase + incl - p;
    if (t < NBK / 2) {
        lofs[2 * t] = ex;
        lofs[2 * t + 1] = ex + h0;
    }
    if (t < NBK) gofs[t] = atomicAdd(&gcur[(segbase + t) * GSTR], hist[t]);
    if (t + 256 < NBK)
        gofs[t + 256] = atomicAdd(&gcur[(segbase + t + 256) * GSTR], hist[t + 256]);
    __syncthreads();

    // stage at lofs[bucket] + rank (no second atomic); src pairs (16B loads)
#pragma unroll
    for (int k = 0; k < IPT2; ++k) {
        int e = tile0 + k * 512 + 2 * t;
        int s0, s1;
        if (fl) {
            ulonglong2 ss = *(const ulonglong2*)((const long long*)ei + e);
            s0 = (int)ss.x;
            s1 = (int)ss.y;
        } else {
            uint2 ss = *(const uint2*)((const int*)ei + e);
            s0 = (int)ss.x;
            s1 = (int)ss.y;
        }
        unsigned v0 = dr[2 * k], v1 = dr[2 * k + 1];
        int d0 = (int)(v0 & 0x3FFFFu), d1 = (int)(v1 & 0x3FFFFu);
        int r0 = (int)(v0 >> 18), r1 = (int)(v1 >> 18);
        stage[lofs[d0 >> 9] + r0] = ((unsigned)(d0 & 511) << 18) | (unsigned)s0;
        stage[lofs[d1 >> 9] + r1] = ((unsigned)(d1 & 511) << 18) | (unsigned)s1;
    }
    __syncthreads();

    // coalesced write-out; bucket of slot i via binary search on lofs
    for (int i = t; i < TILE; i += 256) {
        int lo = 0, hi = NBK - 1;
#pragma unroll
        for (int it = 0; it < 9; ++it) {
            int mid = (lo + hi + 1) >> 1;
            if (lofs[mid] <= i) lo = mid;
            else hi = mid - 1;
        }
        int b = lo;
        unsigned pack = stage[i];
        int seg = segbase + b;
        int dest = gofs[b] + (i - lofs[b]);
        if (dest < (seg + 1) * SCAP) {
            binned[dest] = pack;
        } else {  // overflow (never in practice)
            int op = atomicAdd(&gcur[NSEG * GSTR], 1);
            if (op < OVFCAP) {
                int d = (b << 9) | (int)(pack >> 18);
                int s = (int)(pack & 0x3FFFF);
                ovf[op] = ((ull)d << 32) | (unsigned)s;
            }
        }
    }
}

// bucket-local counting sort over 8 sub-segments, key = (dlow<<1)|(src>=PHB).
// count -> scan -> cursor-atomic scatter (cnt reused as cursor; order within a
// key is irrelevant downstream). Also computes dinv = rsqrt(degree+1).
__global__ __launch_bounds__(1024, 8) void k_sort(const int* __restrict__ gcur,
                                                  const unsigned* __restrict__ binned,
                                                  const ull* __restrict__ ovf,
                                                  unsigned* __restrict__ csr,
                                                  float* __restrict__ dinv,
                                                  int* __restrict__ rsg,
                                                  unsigned* __restrict__ spl) {
    __shared__ int cnt[1024];
    __shared__ int excl[1024];
    __shared__ int wsum[16];
    int b = blockIdx.x;
    int t = threadIdx.x;
    cnt[t] = 0;
    __syncthreads();
    int nov = min(gcur[NSEG * GSTR], OVFCAP);

    // pass 1: count keys across the 8 sub-segments (fire-and-forget atomics)
    for (int s = 0; s < NSUB; ++s) {
        int seg = s * NBK + b;
        int sb = seg * SCAP;
        int n = min(gcur[seg * GSTR] - sb, SCAP);
        for (int i = t; i < n; i += 1024) {
            unsigned pack = binned[sb + i];
            int key = ((int)(pack >> 18) << 1) | ((pack & 0x3FFFF) >= PHB ? 1 : 0);
            atomicAdd(&cnt[key], 1);
        }
    }
    __syncthreads();

    // exclusive scan of 1024 counts: 64-lane shfl scan + 16-wave combine
    int c = cnt[t];
    int lane = t & 63;
    int w = t >> 6;
    int incl = c;
#pragma unroll
    for (int off = 1; off < 64; off <<= 1) {
        int v = __shfl_up(incl, off, 64);
        if (lane >= off) incl += v;
    }
    if (lane == 63) wsum[w] = incl;
    __syncthreads();
    int wbase = 0;
#pragma unroll
    for (int ww = 0; ww < 16; ++ww) wbase += (ww < w) ? wsum[ww] : 0;
    excl[t] = wbase + incl - c;
    __syncthreads();

    if (t < 512) {
        int g = (b << 9) + t;
        if (g < NN) {
            int c0 = cnt[2 * t];
            int c1 = cnt[2 * t + 1];
            int extra = 0;
            for (int k = 0; k < nov; ++k) extra += ((int)(ovf[k] >> 32) == g);
            dinv[g] = rsqrtf((float)(c0 + c1 + extra) + 1.0f);
            rsg[g] = b * CCAP + excl[2 * t];                 // csr row start (absolute)
            spl[g] = (unsigned)c0 | ((unsigned)c1 << 16);    // phase sub-counts
        }
    }
    __syncthreads();  // dinv readers of cnt done before cursor overwrite

    cnt[t] = b * CCAP + excl[t];  // absolute csr cursor
    __syncthreads();

    // pass 2: scatter via cursor atomics
    for (int s = 0; s < NSUB; ++s) {
        int seg = s * NBK + b;
        int sb = seg * SCAP;
        int n = min(gcur[seg * GSTR] - sb, SCAP);
        for (int i = t; i < n; i += 1024) {
            unsigned pack = binned[sb + i];
            unsigned src = pack & 0x3FFFF;
            int key = ((int)(pack >> 18) << 1) | (src >= PHB ? 1 : 0);
            int pos = atomicAdd(&cnt[key], 1);
            csr[pos] = src;
        }
    }
}

// xph[s] = fp16(dinv[s]*x[s]) padded to 16 halves (one aligned 32B row).
__global__ void k_prep(const float* __restrict__ x, const float* __restrict__ dinv,
                       __half* __restrict__ xph) {
    int i = blockIdx.x * blockDim.x + threadIdx.x;
    if (i >= NN * 16) return;
    int node = i >> 4;
    int c = i & 15;
    float v = (c < IC) ? dinv[node] * x[node * IC + c] : 0.0f;
    xph[i] = __float2half(v);
}

// Layer-1 aggregation. Phase q reads ONLY its csr sub-range (exact partition).
// Gather region = 3.2MB fp16, L2-resident. 4 lanes per dst node.
__global__ __launch_bounds__(256) void k_agg1(const int* __restrict__ rsg,
                                              const unsigned* __restrict__ spl,
                                              const unsigned* __restrict__ csr,
                                              const __half* __restrict__ xph,
                                              float* __restrict__ partial) {
    int t = threadIdx.x;
    int q = (blockIdx.x >= NAGG) ? 1 : 0;
    int blk = blockIdx.x - q * NAGG;
    int g = t >> 2;
    int qq = t & 3;
    int i = blk * 64 + g;
    unsigned sp = spl[i];
    int n0 = (int)(sp & 0xFFFF);
    int n1 = (int)(sp >> 16);
    int beg = rsg[i] + (q ? n0 : 0);
    int end = beg + (q ? n1 : n0);

    float ax = 0.0f, ay = 0.0f, az = 0.0f, aw = 0.0f;
    int j = beg;
    for (; j + 1 < end; j += 2) {
        int s0 = csr[j];
        int s1 = csr[j + 1];
        uint2 u0 = *(const uint2*)(xph + (size_t)s0 * 16 + 4 * qq);
        uint2 u1 = *(const uint2*)(xph + (size_t)s1 * 16 + 4 * qq);
        float2 f0 = __half22float2(*(__half2*)&u0.x);
        float2 f1 = __half22float2(*(__half2*)&u0.y);
        float2 f2 = __half22float2(*(__half2*)&u1.x);
        float2 f3 = __half22float2(*(__half2*)&u1.y);
        ax += f0.x + f2.x;
        ay += f0.y + f2.y;
        az += f1.x + f3.x;
        aw += f1.y + f3.y;
    }
    if (j < end) {
        uint2 u0 = *(const uint2*)(xph + (size_t)csr[j] * 16 + 4 * qq);
        float2 f0 = __half22float2(*(__half2*)&u0.x);
        float2 f1 = __half22float2(*(__half2*)&u0.y);
        ax += f0.x;
        ay += f0.y;
        az += f1.x;
        aw += f1.y;
    }
    float4 r = {ax, ay, az, aw};
    *(float4*)(partial + ((size_t)q * NN + i) * 16 + 4 * qq) = r;
}

// Sum phase partials + self loop + overflow-list fixup, then the fused MLP.
__global__ __launch_bounds__(256) void k_mlp(const float* __restrict__ partial,
                                             const __half* __restrict__ xph,
                                             const int* __restrict__ gcur,
                                             const ull* __restrict__ ovf,
                                             const float* __restrict__ dinv,
                                             const float* __restrict__ W1,
                                             const float* __restrict__ b1,
                                             const float* __restrict__ W2,
                                             const float* __restrict__ b2,
                                             float2* __restrict__ h2bp,
                                             float2* __restrict__ selfout) {
    __shared__ float sW1[IC * HC];
    __shared__ float sb1[HC];
    __shared__ float sW2[HC * OC];
    __shared__ float sb2[OC];
    int t = threadIdx.x;
    if (t < IC * HC) sW1[t] = W1[t];
    if (t < HC) sb1[t] = b1[t];
    if (t < HC * OC) sW2[t] = W2[t];
    if (t < OC) sb2[t] = b2[t];
    __syncthreads();

    int i = blockIdx.x * 256 + t;
    if (i >= NN) return;

    float dv = dinv[i];
    const float4* p0 = (const float4*)(partial + (size_t)i * 16);
    const float4* p1 = (const float4*)(partial + ((size_t)NN + i) * 16);
    const uint2* sp = (const uint2*)(xph + (size_t)i * 16);

    float agg[16];
#pragma unroll
    for (int c4 = 0; c4 < 4; ++c4) {
        float4 a = p0[c4];
        float4 b = p1[c4];
        uint2 u = sp[c4];
        float2 s0 = __half22float2(*(__half2*)&u.x);
        float2 s1 = __half22float2(*(__half2*)&u.y);
        agg[4 * c4 + 0] = a.x + b.x + s0.x;
        agg[4 * c4 + 1] = a.y + b.y + s0.y;
        agg[4 * c4 + 2] = a.z + b.z + s1.x;
        agg[4 * c4 + 3] = a.w + b.w + s1.y;
    }

    // overflow fixup (nov==0 in practice)
    int nov = min(gcur[NSEG * GSTR], OVFCAP);
    for (int k = 0; k < nov; ++k) {
        ull e = ovf[k];
        if ((int)(e >> 32) == i) {
            int s = (int)(e & 0xFFFFFFFFu);
            for (int c = 0; c < IC; ++c)
                agg[c] += __half2float(xph[(size_t)s * 16 + c]);
        }
    }

    float tt[IC];
#pragma unroll
    for (int c = 0; c < IC; ++c) tt[c] = dv * agg[c];

    float r[HC];
#pragma unroll
    for (int f = 0; f < HC; ++f) {
        float a = sb1[f];
#pragma unroll
        for (int c = 0; c < IC; ++c) a = fmaf(tt[c], sW1[c * HC + f], a);
        r[f] = fmaxf(a, 0.0f);
    }

    float o0 = 0.0f, o1 = 0.0f;
#pragma unroll
    for (int f = 0; f < HC; ++f) {
        o0 = fmaf(r[f], sW2[f * OC + 0], o0);
        o1 = fmaf(r[f], sW2[f * OC + 1], o1);
    }
    h2bp[i] = make_float2(o0 * dv, o1 * dv);  // dinv-prescaled for layer 2
    selfout[i] = make_float2(o0 * dv * dv + sb2[0], o1 * dv * dv + sb2[1]);
}

// layer-2: out[i] = selfout[i] + dinv[i] * (sum h2bp[src] + ovf matches).
// 2 lanes per node (split edge range), shfl_xor combine.
__global__ __launch_bounds__(256) void k_agg2(const int* __restrict__ rsg,
                                              const unsigned* __restrict__ spl,
                                              const unsigned* __restrict__ csr,
                                              const int* __restrict__ gcur,
                                              const ull* __restrict__ ovf,
                                              const float* __restrict__ dinv,
                                              const float2* __restrict__ h2bp,
                                              const float2* __restrict__ selfout,
                                              float2* __restrict__ out) {
    int tt = blockIdx.x * 256 + threadIdx.x;
    int i = tt >> 1;
    int h = tt & 1;
    if (i >= NN) return;
    unsigned sp = spl[i];
    int beg = rsg[i];
    int end = beg + (int)(sp & 0xFFFF) + (int)(sp >> 16);
    float ax = 0.0f, ay = 0.0f;
    int j = beg + h;
    for (; j + 2 < end; j += 4) {
        float2 h0 = h2bp[csr[j]];
        float2 h1 = h2bp[csr[j + 2]];
        ax += h0.x + h1.x;
        ay += h0.y + h1.y;
    }
    if (j < end) {
        float2 h0 = h2bp[csr[j]];
        ax += h0.x;
        ay += h0.y;
    }
    ax += __shfl_xor(ax, 1);
    ay += __shfl_xor(ay, 1);
    if (h == 0) {
        // overflow fixup (nov==0 in practice); h2bp already dinv[src]-prescaled
        int nov = min(gcur[NSEG * GSTR], OVFCAP);
        for (int k = 0; k < nov; ++k) {
            ull e = ovf[k];
            if ((int)(e >> 32) == i) {
                float2 hh = h2bp[(int)(e & 0xFFFFFFFFu)];
                ax += hh.x;
                ay += hh.y;
            }
        }
        float dv = dinv[i];
        float2 so = selfout[i];
        out[i] = make_float2(so.x + dv * ax, so.y + dv * ay);
    }
}

extern "C" void kernel_launch(void* const* d_in, const int* in_sizes, int n_in,
                              void* d_out, int out_size, void* d_ws, size_t ws_size,
                              hipStream_t stream) {
    const float* x = (const float*)d_in[0];
    const void* ei = d_in[1];
    // d_in[2] = edge_attr (unused)
    const float* W1 = (const float*)d_in[3];
    const float* b1 = (const float*)d_in[4];
    const float* W2 = (const float*)d_in[5];
    const float* b2 = (const float*)d_in[6];
    float* out = (float*)d_out;

    ull* ovf = (ull*)d_ws;                              // OVFCAP       (0.5MB)
    int* gcur = (int*)(ovf + OVFCAP);                   // (NSEG+1)*16 ints (200KB)
    int* flag = gcur + (NSEG + 1) * GSTR;               // 4
    int* rsg = flag + 4;                                // NN
    unsigned* spl = (unsigned*)(rsg + NN);              // NN
    float* dinv = (float*)(spl + NN);                   // NN
    __half* xph = (__half*)(dinv + NN);                 // NN*16 halves (6.4MB)
    float2* h2bp = (float2*)(xph + (size_t)NN * 16);    // NN
    float2* selfout = h2bp + NN;                        // NN
    unsigned* binned = (unsigned*)(selfout + NN);       // NSEG*SCAP    (35.3MB)
    float* partial = (float*)binned;                    // 2*NN*16 f32 (25.6MB), overlays
                                                        // binned (dead after k_sort)
    unsigned* csr = binned + (size_t)NSEG * SCAP;       // NBK*CCAP     (35.3MB)

    k_init<<<(NSEG + 1 + 255) / 256, 256, 0, stream>>>(gcur, ei, flag);
    k_binA<<<NTILE, 256, 0, stream>>>(ei, flag, gcur, binned, ovf);
    k_sort<<<NBK, 1024, 0, stream>>>(gcur, binned, ovf, csr, dinv, rsg, spl);
    k_prep<<<(NN * 16 + 255) / 256, 256, 0, stream>>>(x, dinv, xph);
    k_agg1<<<2 * NAGG, 256, 0, stream>>>(rsg, spl, csr, xph, partial);
    k_mlp<<<NB, 256, 0, stream>>>(partial, xph, gcur, ovf, dinv, W1, b1, W2, b2,
                                  h2bp, selfout);
    k_agg2<<<(NN * 2 + 255) / 256, 256, 0, stream>>>(rsg, spl, csr, gcur, ovf, dinv,
                                                     h2bp, selfout, (float2*)out);
}